// Round 7
// baseline (31892.908 us; speedup 1.0000x reference)
//
#include <hip/hip_runtime.h>
#include <hip/hip_fp16.h>

typedef unsigned short ushort_t;
typedef unsigned int uint_t;

#define BN 512
#define LN 1024
#define FN 38
#define HN 256
#define ZDN 4
#define FXN 64
#define FZN 32

#define NT 512
#define NWG 256

__device__ __forceinline__ ushort_t f2h(float f) { return __half_as_ushort(__float2half(f)); }
__device__ __forceinline__ float h2f(ushort_t u) { return __half2float(__ushort_as_half(u)); }
__device__ __forceinline__ uint_t pk2(float a, float b) {
    return (uint_t)f2h(a) | ((uint_t)f2h(b) << 16);
}

#if defined(__has_builtin)
#if __has_builtin(__builtin_amdgcn_fdot2)
#define HAVE_FDOT2 1
#endif
#endif

typedef _Float16 hv2 __attribute__((ext_vector_type(2)));

__device__ __forceinline__ float dot2h(uint_t w, uint_t a, float acc) {
#ifdef HAVE_FDOT2
    return __builtin_amdgcn_fdot2(__builtin_bit_cast(hv2, w), __builtin_bit_cast(hv2, a), acc, false);
#else
    return acc + h2f((ushort_t)w) * h2f((ushort_t)a)
               + h2f((ushort_t)(w >> 16)) * h2f((ushort_t)(a >> 16));
#endif
}

__device__ __forceinline__ float sigmoidf_(float v) { return 1.0f / (1.0f + expf(-v)); }
__device__ __forceinline__ float softplusf_(float v) {
    return fmaxf(v, 0.0f) + log1pf(expf(-fabsf(v)));
}

// Per-thread register slab, thread t: j2 = t>>1 (row j), kh = t&1 (k-half).
// act coords: [h(256) | fx(64) | fz(32)] = 352. Slices: r/z: [176kh,176kh+176);
// in: x-k [48kh,+48); units n: 0..43 r, 44..87 z, 88..99 in. uint layout [n][t][2].
__global__ __launch_bounds__(256) void repack_slab(const float* __restrict__ W_ih,
                                                   const float* __restrict__ W_hh,
                                                   uint_t* __restrict__ slab) {
    int uid = blockIdx.x * 256 + threadIdx.x;
    if (uid >= 100 * 1024) return;
    int n = uid >> 10, rem = uid & 1023, t = rem >> 1, hw = rem & 1;
    int j2 = t >> 1, kh = t & 1;
    float v0, v1;
    if (n < 88) {
        int g = (n < 44) ? 0 : 1;
        int ki = n - g * 44;
        int ak = 176 * kh + 4 * ki + 2 * hw;   // even; pair never crosses 256
        int row = g * 256 + j2;
        v0 = (ak < 256) ? W_hh[row * 256 + ak] : W_ih[row * 96 + (ak - 256)];
        v1 = (ak + 1 < 256) ? W_hh[row * 256 + ak + 1] : W_ih[row * 96 + (ak + 1 - 256)];
    } else {
        int ki = n - 88;
        int xk = 48 * kh + 4 * ki + 2 * hw;
        v0 = W_ih[(512 + j2) * 96 + xk];
        v1 = W_ih[(512 + j2) * 96 + xk + 1];
    }
    slab[uid] = pk2(v0, v1);
}

// hn-gate weights: whn_ws[row r][128 uints], uint u <-> k {2u, 2u+1}
__global__ __launch_bounds__(256) void repack_whn(const float* __restrict__ W_hh,
                                                  uint_t* __restrict__ whn_ws) {
    int uid = blockIdx.x * 256 + threadIdx.x;
    if (uid >= 256 * 128) return;
    int r = uid >> 7, u = uid & 127;
    whn_ws[uid] = pk2(W_hh[(512 + r) * 256 + 2 * u], W_hh[(512 + r) * 256 + 2 * u + 1]);
}

// phi weights f16: [c(0..3 loc, 4..7 scale)][160 uints]
__global__ __launch_bounds__(256) void repack_wp(const float* __restrict__ Wp_loc,
                                                 const float* __restrict__ Wp_scale,
                                                 uint_t* __restrict__ wpg) {
    int uid = blockIdx.x * 256 + threadIdx.x;
    if (uid >= 8 * 160) return;
    int c = uid / 160, u = uid % 160;
    const float* src = (c < 4) ? (Wp_loc + c * 320) : (Wp_scale + (c - 4) * 320);
    wpg[uid] = pk2(src[2 * u], src[2 * u + 1]);
}

// theta weights f16: [38][144 uints], k-order cat(fz, h) as in Wt_loc
__global__ __launch_bounds__(256) void repack_wt(const float* __restrict__ Wt_loc,
                                                 uint_t* __restrict__ wtg) {
    int uid = blockIdx.x * 256 + threadIdx.x;
    if (uid >= 38 * 144) return;
    wtg[uid] = pk2(Wt_loc[2 * uid], Wt_loc[2 * uid + 1]);
}

// fx = relu(x @ Wx^T + bx) for all (b,l), stored f16-packed [B][L][64].
__global__ __launch_bounds__(256) void fx_pre(const float* __restrict__ x,
                                              const float* __restrict__ Wx,
                                              const float* __restrict__ bx,
                                              ushort_t* __restrict__ fxbuf) {
    __shared__ float w[FXN][FN + 1];
    __shared__ float bxs[FXN];
    int t = threadIdx.x;
    for (int i = t; i < FXN * FN; i += 256) w[i / FN][i % FN] = Wx[i];
    if (t < FXN) bxs[t] = bx[t];
    __syncthreads();
    size_t id = (size_t)blockIdx.x * 256 + t;
    const float* xr = x + id * FN;
    float xv[FN];
#pragma unroll
    for (int f = 0; f < FN; ++f) xv[f] = xr[f];
    uint4* dst = (uint4*)(fxbuf + id * FXN);
#pragma unroll
    for (int e8 = 0; e8 < 8; ++e8) {
        float a[8];
#pragma unroll
        for (int u = 0; u < 8; ++u) {
            int e = e8 * 8 + u;
            float acc = bxs[e];
#pragma unroll
            for (int f = 0; f < FN; ++f) acc += xv[f] * w[e][f];
            a[u] = fmaxf(acc, 0.0f);
        }
        uint4 o;
        o.x = pk2(a[0], a[1]); o.y = pk2(a[2], a[3]);
        o.z = pk2(a[4], a[5]); o.w = pk2(a[6], a[7]);
        dst[e8] = o;
    }
}

#define RZ_STEP(i) { \
    uint4 x0 = A0[22 * kh + (i)]; \
    uint4 x1 = A1[22 * kh + (i)]; \
    uint2 wa = wr[2 * (i)], wb = wr[2 * (i) + 1]; \
    ar0 = dot2h(wa.x, x0.x, ar0); ar0 = dot2h(wa.y, x0.y, ar0); \
    ar0 = dot2h(wb.x, x0.z, ar0); ar0 = dot2h(wb.y, x0.w, ar0); \
    ar1 = dot2h(wa.x, x1.x, ar1); ar1 = dot2h(wa.y, x1.y, ar1); \
    ar1 = dot2h(wb.x, x1.z, ar1); ar1 = dot2h(wb.y, x1.w, ar1); \
    uint2 za = wz[2 * (i)], zb = wz[2 * (i) + 1]; \
    az0 = dot2h(za.x, x0.x, az0); az0 = dot2h(za.y, x0.y, az0); \
    az0 = dot2h(zb.x, x0.z, az0); az0 = dot2h(zb.y, x0.w, az0); \
    az1 = dot2h(za.x, x1.x, az1); az1 = dot2h(za.y, x1.y, az1); \
    az1 = dot2h(zb.x, x1.z, az1); az1 = dot2h(zb.y, x1.w, az1); }

template <bool FXPRE>
__global__ __launch_bounds__(NT) __attribute__((amdgpu_waves_per_eu(2)))
void vrnn_main(
    const float* __restrict__ x, const float* __restrict__ eps,
    const float* __restrict__ Wx, const float* __restrict__ bx,
    const float* __restrict__ Wz1, const float* __restrict__ bz1,
    const float* __restrict__ Wz2, const float* __restrict__ bz2,
    const float* __restrict__ bp_loc, const float* __restrict__ bp_scale,
    const float* __restrict__ bt_loc,
    const float* __restrict__ b_ih, const float* __restrict__ b_hh,
    const uint_t* __restrict__ slab, const uint_t* __restrict__ whn_ws,
    const uint_t* __restrict__ wpg, const uint_t* __restrict__ wtg,
    const ushort_t* __restrict__ fxbuf,
    float* __restrict__ out)
{
    // hn weights lane-linear: hnw4[i*512 + t] = 16B unit for thread t, chunk i.
    // A wave's ds_read_b128 at [i*512+t] is 64 consecutive 16B units -> conflict-free.
    __shared__ __attribute__((aligned(16))) uint_t hnw[16 * 512 * 4];
    __shared__ uint_t wpH[8 * 160];                    // phi weights f16
    __shared__ __attribute__((aligned(16))) uint_t actp[2][2][176];  // f16 acts, dbuf
    __shared__ float pp[2][8][16];
    __shared__ float wz1s[16][ZDN];
    __shared__ float wz2s[FZN][16];
    __shared__ float bz1s[16], bz2s[FZN], btls[FN], bpls[ZDN], bpss[ZDN];
    __shared__ float epsb[2][ZDN];

    const int t = threadIdx.x;
    const int b0 = blockIdx.x * 2;
    const int j2 = t >> 1, kh = t & 1;

    // ---- one-time LDS init
    {
        uint4* hd = (uint4*)hnw;
        for (int i = t; i < 16 * 512; i += NT) {
            int ch = i >> 9, tt = i & 511;
            hd[ch * 512 + tt] = *(const uint4*)&whn_ws[(tt >> 1) * 128 + (tt & 1) * 64 + ch * 4];
        }
    }
    for (int i = t; i < 8 * 160; i += NT) wpH[i] = wpg[i];
    if (t < 64) ((float*)wz1s)[t] = Wz1[t];
    for (int i = t; i < FZN * 16; i += NT) ((float*)wz2s)[i] = Wz2[i];
    if (t < 16) bz1s[t] = bz1[t];
    if (t >= 32 && t < 64) bz2s[t - 32] = bz2[t - 32];
    if (t >= 64 && t < 64 + FN) btls[t - 64] = bt_loc[t - 64];
    if (t >= 128 && t < 132) bpls[t - 128] = bp_loc[t - 128];
    if (t >= 160 && t < 164) bpss[t - 160] = bp_scale[t - 160];
    // zero only h region of buffer 0 (everything else is written before read)
    if (t < 256) actp[0][t >> 7][t & 127] = 0u;
    if (t >= 448 && t < 456) {
        int m = (t >> 2) & 1, c = t & 3;
        epsb[m][c] = eps[(size_t)(b0 + m) * ZDN + c];
    }
    if (FXPRE && t >= 480 && t < 496) {
        int m = (t >> 3) & 1, p = t & 7;
        uint4 v = *(const uint4*)(fxbuf + ((size_t)(b0 + m) * LN) * FXN + p * 8);
        uint_t* d = &actp[0][m][128 + p * 4];
        d[0] = v.x; d[1] = v.y; d[2] = v.z; d[3] = v.w;
    }

    // ---- persistent register weights: 200 VGPRs (fits the 256 cap at 2 waves/EU)
    const uint2* S2 = (const uint2*)slab;
    uint2 wr[44], wz[44], wi[12];
#pragma unroll
    for (int n = 0; n < 44; ++n) wr[n] = S2[n * 512 + t];
#pragma unroll
    for (int n = 0; n < 44; ++n) wz[n] = S2[(44 + n) * 512 + t];
#pragma unroll
    for (int n = 0; n < 12; ++n) wi[n] = S2[(88 + n) * 512 + t];

    const float bsr_o = b_ih[j2] + b_hh[j2];
    const float bsz_o = b_ih[HN + j2] + b_hh[HN + j2];
    const float bin_o = b_ih[2 * HN + j2];
    const float bhn_o = b_hh[2 * HN + j2];
    float h_own = 0.0f;          // h[m=kh][j2], f32, lives in a register

    __syncthreads();

#pragma unroll 1
    for (int l = 0; l < LN; ++l) {
        const int cur = l & 1, nxt = cur ^ 1;
        const uint_t* Au0 = actp[cur][0];
        const uint_t* Au1 = actp[cur][1];
        const uint4* A0 = (const uint4*)Au0;
        const uint4* A1 = (const uint4*)Au1;

        if (!FXPRE) {
            if (t < 64) {
                int m = t >> 5, e2 = t & 31;
                const float* xr = x + ((size_t)(b0 + m) * LN + l) * FN;
                float a0 = bx[2 * e2], a1 = bx[2 * e2 + 1];
                const float* w0 = Wx + (2 * e2) * FN;
                const float* w1 = w0 + FN;
#pragma unroll
                for (int f = 0; f < FN; ++f) { float xv = xr[f]; a0 += xv * w0[f]; a1 += xv * w1[f]; }
                actp[cur][m][128 + e2] = pk2(fmaxf(a0, 0.0f), fmaxf(a1, 0.0f));
            }
            if (t >= 64 && t < 72) {
                int m = (t >> 2) & 1, c = t & 3;
                epsb[m][c] = eps[((size_t)l * BN + b0 + m) * ZDN + c];
            }
            __syncthreads();
        }

        // prefetch next-step inputs (wave 7)
        float pf_eps = 0.0f;
        uint4 pf_fx = {0, 0, 0, 0};
        if (FXPRE) {
            int lp = (l + 1 < LN) ? l + 1 : LN - 1;
            if (t >= 448 && t < 456) {
                int m = (t >> 2) & 1, c = t & 3;
                pf_eps = eps[((size_t)lp * BN + b0 + m) * ZDN + c];
            }
            if (t >= 480 && t < 496) {
                int m = (t >> 3) & 1, p = t & 7;
                pf_fx = *(const uint4*)(fxbuf + ((size_t)(b0 + m) * LN + lp) * FXN + p * 8);
            }
        }

        // ---- B: phi partials (256 threads), f16 acts x f16 weights
        if (t < 256) {
            int m = t >> 7, r = t & 127, c = r >> 4, ks = r & 15;
            const uint2* wv = (const uint2*)&wpH[c * 160 + ks * 10];
            const uint2* av = (const uint2*)((m ? Au1 : Au0) + ks * 10);
            float acc = 0.0f;
#pragma unroll
            for (int i = 0; i < 5; ++i) {
                uint2 w = wv[i], a = av[i];
                acc = dot2h(w.x, a.x, acc); acc = dot2h(w.y, a.y, acc);
            }
            pp[m][c][ks] = acc;
        }
        __syncthreads();   // sync1: pp ready

        // ---- CDE (wave 0) overlapped with hn + r/z fz-free dots (all waves)
        if (t < 64) {
            int m = t >> 5, qq = t & 31;
            float zz[ZDN];
#pragma unroll
            for (int c = 0; c < ZDN; ++c) {
                float lo = bpls[c], sc = bpss[c];
#pragma unroll
                for (int ks = 0; ks < 16; ++ks) { lo += pp[m][c][ks]; sc += pp[m][c + 4][ks]; }
                zz[c] = lo + softplusf_(sc) * epsb[m][c];
            }
            float acc = bz2s[qq];
#pragma unroll
            for (int k = 0; k < 16; ++k) {
                float a = bz1s[k];
#pragma unroll
                for (int c = 0; c < ZDN; ++c) a += zz[c] * wz1s[k][c];
                acc += fmaxf(a, 0.0f) * wz2s[qq][k];
            }
            float v = fmaxf(acc, 0.0f);
            float oth = __shfl_xor(v, 1);
            if (!(qq & 1)) actp[cur][m][160 + (qq >> 1)] = pk2(v, oth);
        }

        // hn gate (pure h, lane-linear LDS weights -> conflict-free b128 reads)
        float ah0 = 0.0f, ah1 = 0.0f;
        {
            const uint4* wh4 = ((const uint4*)hnw) + t;
#pragma unroll
            for (int i = 0; i < 16; ++i) {
                uint4 w = wh4[i * 512];
                uint4 x0 = A0[16 * kh + i];
                uint4 x1 = A1[16 * kh + i];
                ah0 = dot2h(w.x, x0.x, ah0); ah0 = dot2h(w.y, x0.y, ah0);
                ah0 = dot2h(w.z, x0.z, ah0); ah0 = dot2h(w.w, x0.w, ah0);
                ah1 = dot2h(w.x, x1.x, ah1); ah1 = dot2h(w.y, x1.y, ah1);
                ah1 = dot2h(w.z, x1.z, ah1); ah1 = dot2h(w.w, x1.w, ah1);
            }
        }
        // r/z dots, fz-independent part (kh=0: whole slice is h; kh=1: up to fx)
        float ar0 = 0, ar1 = 0, az0 = 0, az1 = 0;
#pragma unroll
        for (int i = 0; i < 18; ++i) RZ_STEP(i)
        if (kh == 0) {
#pragma unroll
            for (int i = 18; i < 22; ++i) RZ_STEP(i)
        }
        __syncthreads();   // sync2: fz ready

        if (kh == 1) {
#pragma unroll
            for (int i = 18; i < 22; ++i) RZ_STEP(i)
        }
        // in gate
        float ai0 = 0.0f, ai1 = 0.0f;
#pragma unroll
        for (int i = 0; i < 6; ++i) {
            uint4 x0 = A0[32 + 6 * kh + i];
            uint4 x1 = A1[32 + 6 * kh + i];
            uint2 wa = wi[2 * i], wb = wi[2 * i + 1];
            ai0 = dot2h(wa.x, x0.x, ai0); ai0 = dot2h(wa.y, x0.y, ai0);
            ai0 = dot2h(wb.x, x0.z, ai0); ai0 = dot2h(wb.y, x0.w, ai0);
            ai1 = dot2h(wa.x, x1.x, ai1); ai1 = dot2h(wa.y, x1.y, ai1);
            ai1 = dot2h(wb.x, x1.z, ai1); ai1 = dot2h(wb.y, x1.w, ai1);
        }

        // theta (weights streamed from L2-resident global)
        if (t < 304) {
            int o = t >> 2, s4 = t & 3, f = o >> 1, m = o & 1;
            const uint4* wt4 = ((const uint4*)wtg) + f * 36;
            const uint4* ap = m ? A1 : A0;
            float acc = 0.0f;
#pragma unroll
            for (int i2 = 0; i2 < 9; ++i2) {
                int i = s4 * 9 + i2;
                uint4 w = wt4[i];
                uint4 a = (i < 4) ? ap[40 + i] : ap[i - 4];   // fz | h
                acc = dot2h(w.x, a.x, acc); acc = dot2h(w.y, a.y, acc);
                acc = dot2h(w.z, a.z, acc); acc = dot2h(w.w, a.w, acc);
            }
            acc += __shfl_xor(acc, 1);
            acc += __shfl_xor(acc, 2);
            if (!s4) out[((size_t)(b0 + m) * LN + l) * FN + f] = acc + btls[f];
        }

        // combine k-halves (pair lanes) + gates + h update
        {
            float Tr0 = ar0 + __shfl_xor(ar0, 1);
            float Tr1 = ar1 + __shfl_xor(ar1, 1);
            float Tz0 = az0 + __shfl_xor(az0, 1);
            float Tz1 = az1 + __shfl_xor(az1, 1);
            float Ti0 = ai0 + __shfl_xor(ai0, 1);
            float Ti1 = ai1 + __shfl_xor(ai1, 1);
            float Th0 = ah0 + __shfl_xor(ah0, 1);
            float Th1 = ah1 + __shfl_xor(ah1, 1);
            float gr = kh ? Tr1 : Tr0;
            float gz = kh ? Tz1 : Tz0;
            float gi = kh ? Ti1 : Ti0;
            float gh = kh ? Th1 : Th0;
            float r_ = sigmoidf_(gr + bsr_o);
            float z_ = sigmoidf_(gz + bsz_o);
            float n_ = tanhf(gi + bin_o + r_ * (gh + bhn_o));
            float hnew = (1.0f - z_) * n_ + z_ * h_own;
            h_own = hnew;
            float hp = __shfl_xor(hnew, 2);
            if (!(t & 2)) actp[nxt][kh][j2 >> 1] = pk2(hnew, hp);
        }

        // park prefetched inputs into next buffer
        if (FXPRE) {
            if (t >= 448 && t < 456) { int m = (t >> 2) & 1, c = t & 3; epsb[m][c] = pf_eps; }
            if (t >= 480 && t < 496) {
                int m = (t >> 3) & 1, p = t & 7;
                uint_t* d = &actp[nxt][m][128 + p * 4];
                d[0] = pf_fx.x; d[1] = pf_fx.y; d[2] = pf_fx.z; d[3] = pf_fx.w;
            }
        }
        __syncthreads();   // sync3
    }
}

extern "C" void kernel_launch(void* const* d_in, const int* in_sizes, int n_in,
                              void* d_out, int out_size, void* d_ws, size_t ws_size,
                              hipStream_t stream) {
    const float* x        = (const float*)d_in[0];
    const float* eps      = (const float*)d_in[1];
    const float* Wx       = (const float*)d_in[2];
    const float* bx       = (const float*)d_in[3];
    const float* Wz1      = (const float*)d_in[4];
    const float* bz1      = (const float*)d_in[5];
    const float* Wz2      = (const float*)d_in[6];
    const float* bz2      = (const float*)d_in[7];
    const float* Wp_loc   = (const float*)d_in[8];
    const float* bp_loc   = (const float*)d_in[9];
    const float* Wp_scale = (const float*)d_in[10];
    const float* bp_scale = (const float*)d_in[11];
    const float* Wt_loc   = (const float*)d_in[12];
    const float* bt_loc   = (const float*)d_in[13];
    const float* W_ih     = (const float*)d_in[16];
    const float* W_hh     = (const float*)d_in[17];
    const float* b_ih     = (const float*)d_in[18];
    const float* b_hh     = (const float*)d_in[19];
    float* out = (float*)d_out;

    const size_t slabU = 100 * 1024;              // uints
    const size_t whnU  = 256 * 128;
    const size_t wpU   = 8 * 160;
    const size_t wtU   = 38 * 144;
    const size_t fxS   = (size_t)BN * LN * FXN;   // shorts

    uint_t* slab = (uint_t*)d_ws;
    uint_t* whnw = slab + slabU;
    uint_t* wpg  = whnw + whnU;
    uint_t* wtg  = wpg + wpU;
    ushort_t* fxbuf = (ushort_t*)(wtg + wtU);

    repack_slab<<<(int)((slabU + 255) / 256), 256, 0, stream>>>(W_ih, W_hh, slab);
    repack_whn<<<(int)((whnU + 255) / 256), 256, 0, stream>>>(W_hh, whnw);
    repack_wp<<<5, 256, 0, stream>>>(Wp_loc, Wp_scale, wpg);
    repack_wt<<<22, 256, 0, stream>>>(Wt_loc, wtg);

    if (ws_size >= (slabU + whnU + wpU + wtU) * 4 + fxS * 2) {
        fx_pre<<<BN * LN / 256, 256, 0, stream>>>(x, Wx, bx, fxbuf);
        vrnn_main<true><<<NWG, NT, 0, stream>>>(
            x, eps, Wx, bx, Wz1, bz1, Wz2, bz2, bp_loc, bp_scale, bt_loc,
            b_ih, b_hh, slab, whnw, wpg, wtg, fxbuf, out);
    } else {
        vrnn_main<false><<<NWG, NT, 0, stream>>>(
            x, eps, Wx, bx, Wz1, bz1, Wz2, bz2, bp_loc, bp_scale, bt_loc,
            b_ih, b_hh, slab, whnw, wpg, wtg, (const ushort_t*)nullptr, out);
    }
}

// Round 8
// 17352.907 us; speedup vs baseline: 1.8379x; 1.8379x over previous
//
#include <hip/hip_runtime.h>
#include <hip/hip_fp16.h>

typedef unsigned short ushort_t;
typedef unsigned int uint_t;

#define BN 512
#define LN 1024
#define FN 38
#define HN 256
#define ZDN 4
#define FXN 64
#define FZN 32

#define NT 1024
#define NWG 256

__device__ __forceinline__ ushort_t f2h(float f) { return __half_as_ushort(__float2half(f)); }
__device__ __forceinline__ float h2f(ushort_t u) { return __half2float(__ushort_as_half(u)); }
__device__ __forceinline__ uint_t pk2(float a, float b) {
    return (uint_t)f2h(a) | ((uint_t)f2h(b) << 16);
}

#if defined(__has_builtin)
#if __has_builtin(__builtin_amdgcn_fdot2)
#define HAVE_FDOT2 1
#endif
#endif

typedef _Float16 hv2 __attribute__((ext_vector_type(2)));

__device__ __forceinline__ float dot2h(uint_t w, uint_t a, float acc) {
#ifdef HAVE_FDOT2
    return __builtin_amdgcn_fdot2(__builtin_bit_cast(hv2, w), __builtin_bit_cast(hv2, a), acc, false);
#else
    return acc + h2f((ushort_t)w) * h2f((ushort_t)a)
               + h2f((ushort_t)(w >> 16)) * h2f((ushort_t)(a >> 16));
#endif
}

__device__ __forceinline__ float sigmoidf_(float v) { return 1.0f / (1.0f + expf(-v)); }
__device__ __forceinline__ float softplusf_(float v) {
    return fmaxf(v, 0.0f) + log1pf(expf(-fabsf(v)));
}

// r/z register slab: uint2 unit n (0..21 r, 22..43 z) for thread t at slab2[n*1024+t].
// n within gate = rp*11 + ki: row = g*256 + 2*(t>>3) + rp, act-k = 44*(t&7) + 4*ki (+2*hw per uint).
// act coords: [h(256) | fx(64) | fz(32)] = 352; r/z cols: h->W_hh, x->W_ih.
__global__ __launch_bounds__(256) void repack_rz(const float* __restrict__ W_ih,
                                                 const float* __restrict__ W_hh,
                                                 uint_t* __restrict__ slab) {
    int uid = blockIdx.x * 256 + threadIdx.x;     // uints, total 44*1024*2
    if (uid >= 44 * 1024 * 2) return;
    int n = uid >> 11, rem = uid & 2047, t = rem >> 1, hw = rem & 1;
    int g = (n < 22) ? 0 : 1, n2 = n - g * 22;
    int rp = n2 / 11, ki = n2 % 11;
    int row = g * 256 + 2 * (t >> 3) + rp;
    int ak = 44 * (t & 7) + 4 * ki + 2 * hw;
    float v0 = (ak < 256) ? W_hh[row * 256 + ak] : W_ih[row * 96 + ak - 256];
    float v1 = (ak + 1 < 256) ? W_hh[row * 256 + ak + 1] : W_ih[row * 96 + ak + 1 - 256];
    slab[uid] = pk2(v0, v1);
}

// hn weights, lane-linear uint4 units: hnws4[i*1024 + t], i = rp*4 + b:
// row = 512 + 2*(t>>3) + rp, k = 8*((t&7) + 8*b) .. +8  (strided k-blocks).
__global__ __launch_bounds__(256) void repack_hn(const float* __restrict__ W_hh,
                                                 uint_t* __restrict__ hnws) {
    int uid = blockIdx.x * 256 + threadIdx.x;     // uints, total 8*1024*4
    if (uid >= 8 * 1024 * 4) return;
    int i = uid >> 12, rem = uid & 4095, t = rem >> 2, w = rem & 3;
    int rp = i >> 2, b = i & 3;
    int row = 512 + 2 * (t >> 3) + rp;
    int k0 = 8 * ((t & 7) + 8 * b) + 2 * w;
    hnws[uid] = pk2(W_hh[row * 256 + k0], W_hh[row * 256 + k0 + 1]);
}

// in-gate weights streamed: uint2 units wig2[u*1024 + t], u = rp*3 + ui:
// row = 512 + 2*(t>>3) + rp, xk = 12*(t&7) + 4*ui (+2*hw).
__global__ __launch_bounds__(256) void repack_in(const float* __restrict__ W_ih,
                                                 uint_t* __restrict__ wig) {
    int uid = blockIdx.x * 256 + threadIdx.x;     // uints, total 6*1024*2
    if (uid >= 6 * 1024 * 2) return;
    int u = uid >> 11, rem = uid & 2047, t = rem >> 1, hw = rem & 1;
    int rp = u / 3, ui = u % 3;
    int row = 512 + 2 * (t >> 3) + rp;
    int xk = 12 * (t & 7) + 4 * ui + 2 * hw;
    wig[uid] = pk2(W_ih[row * 96 + xk], W_ih[row * 96 + xk + 1]);
}

// phi weights f16: [c(0..3 loc, 4..7 scale)][160 uints] (padded to 162 when copied to LDS)
__global__ __launch_bounds__(256) void repack_wp(const float* __restrict__ Wp_loc,
                                                 const float* __restrict__ Wp_scale,
                                                 uint_t* __restrict__ wpg) {
    int uid = blockIdx.x * 256 + threadIdx.x;
    if (uid >= 8 * 160) return;
    int c = uid / 160, u = uid % 160;
    const float* src = (c < 4) ? (Wp_loc + c * 320) : (Wp_scale + (c - 4) * 320);
    wpg[uid] = pk2(src[2 * u], src[2 * u + 1]);
}

// theta weights f16: [38][144 uints], k-order cat(fz, h)
__global__ __launch_bounds__(256) void repack_wt(const float* __restrict__ Wt_loc,
                                                 uint_t* __restrict__ wtg) {
    int uid = blockIdx.x * 256 + threadIdx.x;
    if (uid >= 38 * 144) return;
    wtg[uid] = pk2(Wt_loc[2 * uid], Wt_loc[2 * uid + 1]);
}

// fx = relu(x @ Wx^T + bx) for all (b,l), stored f16-packed [B][L][64].
__global__ __launch_bounds__(256) void fx_pre(const float* __restrict__ x,
                                              const float* __restrict__ Wx,
                                              const float* __restrict__ bx,
                                              ushort_t* __restrict__ fxbuf) {
    __shared__ float w[FXN][FN + 1];
    __shared__ float bxs[FXN];
    int t = threadIdx.x;
    for (int i = t; i < FXN * FN; i += 256) w[i / FN][i % FN] = Wx[i];
    if (t < FXN) bxs[t] = bx[t];
    __syncthreads();
    size_t id = (size_t)blockIdx.x * 256 + t;
    const float* xr = x + id * FN;
    float xv[FN];
#pragma unroll
    for (int f = 0; f < FN; ++f) xv[f] = xr[f];
    uint4* dst = (uint4*)(fxbuf + id * FXN);
#pragma unroll
    for (int e8 = 0; e8 < 8; ++e8) {
        float a[8];
#pragma unroll
        for (int u = 0; u < 8; ++u) {
            int e = e8 * 8 + u;
            float acc = bxs[e];
#pragma unroll
            for (int f = 0; f < FN; ++f) acc += xv[f] * w[e][f];
            a[u] = fmaxf(acc, 0.0f);
        }
        uint4 o;
        o.x = pk2(a[0], a[1]); o.y = pk2(a[2], a[3]);
        o.z = pk2(a[4], a[5]); o.w = pk2(a[6], a[7]);
        dst[e8] = o;
    }
}

// r/z dot unit u (4 act-k): acts shared across 2 rows x 2 m, weights from regs.
#define RZU(u) { \
    uint2 a0 = A0_2[11 * s8 + (u)]; \
    uint2 a1 = A1_2[11 * s8 + (u)]; \
    uint2 wa = wrA[u], wb = wrB[u]; \
    r00 = dot2h(wa.x, a0.x, r00); r00 = dot2h(wa.y, a0.y, r00); \
    r01 = dot2h(wb.x, a0.x, r01); r01 = dot2h(wb.y, a0.y, r01); \
    r10 = dot2h(wa.x, a1.x, r10); r10 = dot2h(wa.y, a1.y, r10); \
    r11 = dot2h(wb.x, a1.x, r11); r11 = dot2h(wb.y, a1.y, r11); \
    uint2 za = wzA[u], zb = wzB[u]; \
    z00 = dot2h(za.x, a0.x, z00); z00 = dot2h(za.y, a0.y, z00); \
    z01 = dot2h(zb.x, a0.x, z01); z01 = dot2h(zb.y, a0.y, z01); \
    z10 = dot2h(za.x, a1.x, z10); z10 = dot2h(za.y, a1.y, z10); \
    z11 = dot2h(zb.x, a1.x, z11); z11 = dot2h(zb.y, a1.y, z11); }

// 3-stage full butterfly over the 8 k-slice lanes
#define BF(v) { v += __shfl_xor(v, 1); v += __shfl_xor(v, 2); v += __shfl_xor(v, 4); }

template <bool FXPRE>
__global__ __launch_bounds__(NT, 4) __attribute__((amdgpu_waves_per_eu(4, 4)))
void vrnn_main(
    const float* __restrict__ x, const float* __restrict__ eps,
    const float* __restrict__ Wx, const float* __restrict__ bx,
    const float* __restrict__ Wz1, const float* __restrict__ bz1,
    const float* __restrict__ Wz2, const float* __restrict__ bz2,
    const float* __restrict__ bp_loc, const float* __restrict__ bp_scale,
    const float* __restrict__ bt_loc,
    const float* __restrict__ b_ih, const float* __restrict__ b_hh,
    const uint_t* __restrict__ slab, const uint_t* __restrict__ hnsrc,
    const uint_t* __restrict__ wig, const uint_t* __restrict__ wpg,
    const uint_t* __restrict__ wtg, const ushort_t* __restrict__ fxbuf,
    float* __restrict__ out)
{
    __shared__ __attribute__((aligned(16))) uint_t hnw[8 * 1024 * 4];   // 128 KB lane-linear
    __shared__ uint_t wpH[8 * 162];                                     // phi weights (padded)
    __shared__ __attribute__((aligned(16))) uint_t actp[2][2][176];     // f16 acts, dbuf
    __shared__ float pp[2][8][16];
    __shared__ float bsr[HN], bsz[HN], bin_[HN], bhn_[HN];
    __shared__ float wz1s[16][ZDN];
    __shared__ float wz2s[FZN][16];
    __shared__ float bz1s[16], bz2s[FZN], btls[FN], bpls[ZDN], bpss[ZDN];
    __shared__ float epsb[2][ZDN];

    const int t = threadIdx.x;
    const int b0 = blockIdx.x * 2;
    const int jp = t >> 3, s8 = t & 7;

    // ---- one-time LDS init
    {
        uint4* hd = (uint4*)hnw;
        const uint4* hs = (const uint4*)hnsrc;
        for (int i = t; i < 8 * 1024; i += NT) hd[i] = hs[i];
    }
    for (int i = t; i < 8 * 160; i += NT) wpH[(i / 160) * 162 + (i % 160)] = wpg[i];
    if (t < 256) {
        bsr[t] = b_ih[t] + b_hh[t];
        bsz[t] = b_ih[HN + t] + b_hh[HN + t];
        bin_[t] = b_ih[2 * HN + t];
        bhn_[t] = b_hh[2 * HN + t];
    }
    if (t >= 256 && t < 320) ((float*)wz1s)[t - 256] = Wz1[t - 256];
    if (t >= 320 && t < 832) ((float*)wz2s)[t - 320] = Wz2[t - 320];
    if (t >= 832 && t < 848) bz1s[t - 832] = bz1[t - 832];
    if (t >= 848 && t < 880) bz2s[t - 848] = bz2[t - 848];
    if (t >= 880 && t < 880 + FN) btls[t - 880] = bt_loc[t - 880];
    if (t >= 928 && t < 932) bpls[t - 928] = bp_loc[t - 928];
    if (t >= 936 && t < 940) bpss[t - 936] = bp_scale[t - 936];
    // zero h region of buffer 0; prefill l=0 eps / fx
    if (t < 256) actp[0][t >> 7][t & 127] = 0u;
    if (t >= 256 && t < 264) {
        int m = ((t - 256) >> 2) & 1, c = t & 3;
        epsb[m][c] = eps[(size_t)(b0 + m) * ZDN + c];
    }
    if (FXPRE && t >= 272 && t < 304) {
        int tt = t - 272, m = tt >> 4, part = tt & 15;
        uint2 v = ((const uint2*)(fxbuf + ((size_t)(b0 + m) * LN) * FXN))[part];
        actp[0][m][128 + 2 * part] = v.x;
        actp[0][m][129 + 2 * part] = v.y;
    }

    // ---- persistent register weights: r,z = 44 uint2 = 88 VGPRs
    const uint2* S2 = (const uint2*)slab;
    uint2 wrA[11], wrB[11], wzA[11], wzB[11];
#pragma unroll
    for (int k = 0; k < 11; ++k) {
        wrA[k] = S2[k * 1024 + t];
        wrB[k] = S2[(11 + k) * 1024 + t];
        wzA[k] = S2[(22 + k) * 1024 + t];
        wzB[k] = S2[(33 + k) * 1024 + t];
    }

    float h_own = 0.0f;     // lanes s8<4: h(m = s8>>1, j = 2*jp + (s8&1))
    __syncthreads();

#pragma unroll 1
    for (int l = 0; l < LN; ++l) {
        const int cur = l & 1, nxt = cur ^ 1;
        const uint_t* Au0 = actp[cur][0];
        const uint_t* Au1 = actp[cur][1];
        const uint2* A0_2 = (const uint2*)Au0;
        const uint2* A1_2 = (const uint2*)Au1;
        const uint4* A0_4 = (const uint4*)Au0;
        const uint4* A1_4 = (const uint4*)Au1;

        // ---- (tier B only): fx + eps in-loop
        if (!FXPRE) {
            if (t < 64) {
                int m = t >> 5, e2 = t & 31;
                const float* xr = x + ((size_t)(b0 + m) * LN + l) * FN;
                float a0 = bx[2 * e2], a1 = bx[2 * e2 + 1];
                const float* w0 = Wx + (2 * e2) * FN;
                const float* w1 = w0 + FN;
#pragma unroll
                for (int f = 0; f < FN; ++f) { float xv = xr[f]; a0 += xv * w0[f]; a1 += xv * w1[f]; }
                actp[cur][m][128 + e2] = pk2(fmaxf(a0, 0.0f), fmaxf(a1, 0.0f));
            }
            if (t >= 64 && t < 72) {
                int m = (t >> 2) & 1, c = t & 3;
                epsb[m][c] = eps[((size_t)l * BN + b0 + m) * ZDN + c];
            }
            __syncthreads();
        }

        // ---- P2: phi partials (t<256) + issue next-step prefetch
        if (t < 256) {
            int m = t >> 7, r = t & 127, c = r >> 4, ks = r & 15;
            const uint2* wv = (const uint2*)&wpH[c * 162 + ks * 10];
            const uint2* av = (const uint2*)((m ? Au1 : Au0) + ks * 10);
            float acc = 0.0f;
#pragma unroll
            for (int i = 0; i < 5; ++i) {
                uint2 w = wv[i], a = av[i];
                acc = dot2h(w.x, a.x, acc); acc = dot2h(w.y, a.y, acc);
            }
            pp[m][c][ks] = acc;
        }
        float pf_eps = 0.0f;
        uint2 pf_fx = {0, 0};
        if (FXPRE) {
            int lp = (l + 1 < LN) ? l + 1 : LN - 1;
            if (t >= 952 && t < 960) {
                int tt = t - 952, m = tt >> 2, c = tt & 3;
                pf_eps = eps[((size_t)lp * BN + b0 + m) * ZDN + c];
            }
            if (t >= 960 && t < 992) {
                int tt = t - 960, m = tt >> 4, part = tt & 15;
                pf_fx = ((const uint2*)(fxbuf + ((size_t)(b0 + m) * LN + lp) * FXN))[part];
            }
        }
        __syncthreads();   // sync1: pp ready

        // ---- P3: CDE (t<64) overlapped with r/z dots (fz-free units)
        if (t < 64) {
            int m = t >> 5, qq = t & 31;
            float zz[ZDN];
#pragma unroll
            for (int c = 0; c < ZDN; ++c) {
                float lo = bpls[c], sc = bpss[c];
#pragma unroll
                for (int ks = 0; ks < 16; ++ks) { lo += pp[m][c][ks]; sc += pp[m][c + 4][ks]; }
                zz[c] = lo + softplusf_(sc) * epsb[m][c];
            }
            float acc = bz2s[qq];
#pragma unroll
            for (int k = 0; k < 16; ++k) {
                float a = bz1s[k];
#pragma unroll
                for (int c = 0; c < ZDN; ++c) a += zz[c] * wz1s[k][c];
                acc += fmaxf(a, 0.0f) * wz2s[qq][k];
            }
            float v = fmaxf(acc, 0.0f);
            float oth = __shfl_xor(v, 1);
            if (!(qq & 1)) actp[cur][m][160 + (qq >> 1)] = pk2(v, oth);
        }

        float r00 = 0, r01 = 0, r10 = 0, r11 = 0;
        float z00 = 0, z01 = 0, z10 = 0, z11 = 0;
#pragma unroll
        for (int u = 0; u < 3; ++u) RZU(u)
        if (s8 != 7) {
#pragma unroll
            for (int u = 3; u < 11; ++u) RZU(u)
        }
        __syncthreads();   // sync2: fz ready

        // ---- P4: fz-dependent tail, combines, hn, in, theta, gate update
        if (s8 == 7) {
#pragma unroll
            for (int u = 3; u < 11; ++u) RZU(u)
        }
        BF(r00) BF(r01) BF(r10) BF(r11) BF(z00) BF(z01) BF(z10) BF(z11)
        const int m_own = s8 >> 1, rp_own = s8 & 1;
        float gr = m_own ? (rp_own ? r11 : r10) : (rp_own ? r01 : r00);
        float gz = m_own ? (rp_own ? z11 : z10) : (rp_own ? z01 : z00);

        // hn gate: LDS lane-linear weights, strided k-blocks (conflict-free)
        float h00 = 0, h01 = 0, h10 = 0, h11 = 0;
        {
            const uint4* hn4 = (const uint4*)hnw;
#pragma unroll
            for (int b = 0; b < 4; ++b) {
                uint4 a0 = A0_4[s8 + 8 * b];
                uint4 a1 = A1_4[s8 + 8 * b];
                uint4 w0 = hn4[b * 1024 + t];
                uint4 w1 = hn4[(4 + b) * 1024 + t];
                h00 = dot2h(w0.x, a0.x, h00); h00 = dot2h(w0.y, a0.y, h00);
                h00 = dot2h(w0.z, a0.z, h00); h00 = dot2h(w0.w, a0.w, h00);
                h01 = dot2h(w1.x, a0.x, h01); h01 = dot2h(w1.y, a0.y, h01);
                h01 = dot2h(w1.z, a0.z, h01); h01 = dot2h(w1.w, a0.w, h01);
                h10 = dot2h(w0.x, a1.x, h10); h10 = dot2h(w0.y, a1.y, h10);
                h10 = dot2h(w0.z, a1.z, h10); h10 = dot2h(w0.w, a1.w, h10);
                h11 = dot2h(w1.x, a1.x, h11); h11 = dot2h(w1.y, a1.y, h11);
                h11 = dot2h(w1.z, a1.z, h11); h11 = dot2h(w1.w, a1.w, h11);
            }
        }
        BF(h00) BF(h01) BF(h10) BF(h11)
        float gh = m_own ? (rp_own ? h11 : h10) : (rp_own ? h01 : h00);

        // in gate: weights streamed from L2 (sequenced loads, low reg pressure)
        float i00 = 0, i01 = 0, i10 = 0, i11 = 0;
        {
            const uint2* G2 = (const uint2*)wig;
#pragma unroll
            for (int ui = 0; ui < 3; ++ui) {
                uint2 w0 = G2[ui * 1024 + t];
                uint2 w1 = G2[(3 + ui) * 1024 + t];
                uint2 a0 = A0_2[64 + 3 * s8 + ui];
                uint2 a1 = A1_2[64 + 3 * s8 + ui];
                i00 = dot2h(w0.x, a0.x, i00); i00 = dot2h(w0.y, a0.y, i00);
                i01 = dot2h(w1.x, a0.x, i01); i01 = dot2h(w1.y, a0.y, i01);
                i10 = dot2h(w0.x, a1.x, i10); i10 = dot2h(w0.y, a1.y, i10);
                i11 = dot2h(w1.x, a1.x, i11); i11 = dot2h(w1.y, a1.y, i11);
            }
        }
        BF(i00) BF(i01) BF(i10) BF(i11)
        float gi = m_own ? (rp_own ? i11 : i10) : (rp_own ? i01 : i00);

        // theta (t in [320,624)): streamed weights, 4-way k-split
        if (t >= 320 && t < 624) {
            int tt = t - 320, o = tt >> 2, s4 = tt & 3, f = o >> 1, m = o & 1;
            const uint4* wt4 = ((const uint4*)wtg) + f * 36;
            const uint4* ap = m ? A1_4 : A0_4;
            float acc = 0.0f;
#pragma unroll
            for (int i2 = 0; i2 < 9; ++i2) {
                int i = s4 * 9 + i2;
                uint4 w = wt4[i];
                uint4 a = (i < 4) ? ap[40 + i] : ap[i - 4];   // fz | h
                acc = dot2h(w.x, a.x, acc); acc = dot2h(w.y, a.y, acc);
                acc = dot2h(w.z, a.z, acc); acc = dot2h(w.w, a.w, acc);
            }
            acc += __shfl_xor(acc, 1);
            acc += __shfl_xor(acc, 2);
            if (!s4) out[((size_t)(b0 + m) * LN + l) * FN + f] = acc + btls[f];
        }

        // gate math + h update: lanes s8<4 own (m_own, j = 2jp + rp_own)
        if (s8 < 4) {
            int j = 2 * jp + rp_own;
            float r_ = sigmoidf_(gr + bsr[j]);
            float z_ = sigmoidf_(gz + bsz[j]);
            float n_ = tanhf(gi + bin_[j] + r_ * (gh + bhn_[j]));
            float hnew = (1.0f - z_) * n_ + z_ * h_own;
            h_own = hnew;
            float hp = __shfl_xor(hnew, 1);            // pair rows j, j^1 (lanes c, c^1)
            if (!rp_own) actp[nxt][m_own][jp] = pk2(hnew, hp);
        }

        // park prefetched inputs into next-step buffers
        if (FXPRE) {
            if (t >= 952 && t < 960) {
                int tt = t - 952, m = tt >> 2, c = tt & 3;
                epsb[m][c] = pf_eps;
            }
            if (t >= 960 && t < 992) {
                int tt = t - 960, m = tt >> 4, part = tt & 15;
                actp[nxt][m][128 + 2 * part] = pf_fx.x;
                actp[nxt][m][129 + 2 * part] = pf_fx.y;
            }
        }
        __syncthreads();   // sync3
    }
}

extern "C" void kernel_launch(void* const* d_in, const int* in_sizes, int n_in,
                              void* d_out, int out_size, void* d_ws, size_t ws_size,
                              hipStream_t stream) {
    const float* x        = (const float*)d_in[0];
    const float* eps      = (const float*)d_in[1];
    const float* Wx       = (const float*)d_in[2];
    const float* bx       = (const float*)d_in[3];
    const float* Wz1      = (const float*)d_in[4];
    const float* bz1      = (const float*)d_in[5];
    const float* Wz2      = (const float*)d_in[6];
    const float* bz2      = (const float*)d_in[7];
    const float* Wp_loc   = (const float*)d_in[8];
    const float* bp_loc   = (const float*)d_in[9];
    const float* Wp_scale = (const float*)d_in[10];
    const float* bp_scale = (const float*)d_in[11];
    const float* Wt_loc   = (const float*)d_in[12];
    const float* bt_loc   = (const float*)d_in[13];
    const float* W_ih     = (const float*)d_in[16];
    const float* W_hh     = (const float*)d_in[17];
    const float* b_ih     = (const float*)d_in[18];
    const float* b_hh     = (const float*)d_in[19];
    float* out = (float*)d_out;

    const size_t slabU = (size_t)44 * 1024 * 2;   // uints
    const size_t hnU   = (size_t)8 * 1024 * 4;
    const size_t wigU  = (size_t)6 * 1024 * 2;
    const size_t wpU   = 8 * 160;
    const size_t wtU   = 38 * 144;
    const size_t fxS   = (size_t)BN * LN * FXN;   // shorts

    uint_t* slab  = (uint_t*)d_ws;
    uint_t* hnsrc = slab + slabU;
    uint_t* wig   = hnsrc + hnU;
    uint_t* wpg   = wig + wigU;
    uint_t* wtg   = wpg + wpU;
    ushort_t* fxbuf = (ushort_t*)(wtg + wtU);

    repack_rz<<<(int)((slabU + 255) / 256), 256, 0, stream>>>(W_ih, W_hh, slab);
    repack_hn<<<(int)((hnU + 255) / 256), 256, 0, stream>>>(W_hh, hnsrc);
    repack_in<<<(int)((wigU + 255) / 256), 256, 0, stream>>>(W_ih, wig);
    repack_wp<<<5, 256, 0, stream>>>(Wp_loc, Wp_scale, wpg);
    repack_wt<<<22, 256, 0, stream>>>(Wt_loc, wtg);

    if (ws_size >= (slabU + hnU + wigU + wpU + wtU) * 4 + fxS * 2) {
        fx_pre<<<BN * LN / 256, 256, 0, stream>>>(x, Wx, bx, fxbuf);
        vrnn_main<true><<<NWG, NT, 0, stream>>>(
            x, eps, Wx, bx, Wz1, bz1, Wz2, bz2, bp_loc, bp_scale, bt_loc,
            b_ih, b_hh, slab, hnsrc, wig, wpg, wtg, fxbuf, out);
    } else {
        vrnn_main<false><<<NWG, NT, 0, stream>>>(
            x, eps, Wx, bx, Wz1, bz1, Wz2, bz2, bp_loc, bp_scale, bt_loc,
            b_ih, b_hh, slab, hnsrc, wig, wpg, wtg, (const ushort_t*)nullptr, out);
    }
}

// Round 9
// 17322.684 us; speedup vs baseline: 1.8411x; 1.0017x over previous
//
#include <hip/hip_runtime.h>
#include <hip/hip_fp16.h>

typedef unsigned short ushort_t;
typedef unsigned int uint_t;

#define BN 512
#define LN 1024
#define FN 38
#define HN 256
#define ZDN 4
#define FXN 64
#define FZN 32

#define NT 1024
#define NWG 256

__device__ __forceinline__ ushort_t f2h(float f) { return __half_as_ushort(__float2half(f)); }
__device__ __forceinline__ float h2f(ushort_t u) { return __half2float(__ushort_as_half(u)); }
__device__ __forceinline__ uint_t pk2(float a, float b) {
    return (uint_t)f2h(a) | ((uint_t)f2h(b) << 16);
}

#if defined(__has_builtin)
#if __has_builtin(__builtin_amdgcn_fdot2)
#define HAVE_FDOT2 1
#endif
#endif

typedef _Float16 hv2 __attribute__((ext_vector_type(2)));

__device__ __forceinline__ float dot2h(uint_t w, uint_t a, float acc) {
#ifdef HAVE_FDOT2
    return __builtin_amdgcn_fdot2(__builtin_bit_cast(hv2, w), __builtin_bit_cast(hv2, a), acc, false);
#else
    return acc + h2f((ushort_t)w) * h2f((ushort_t)a)
               + h2f((ushort_t)(w >> 16)) * h2f((ushort_t)(a >> 16));
#endif
}

__device__ __forceinline__ float sigmoidf_(float v) { return 1.0f / (1.0f + expf(-v)); }
__device__ __forceinline__ float softplusf_(float v) {
    return fmaxf(v, 0.0f) + log1pf(expf(-fabsf(v)));
}

// r/z register slab: uint2 unit n (0..21 r, 22..43 z) for thread t at slab2[n*1024+t].
// n within gate = rp*11 + ki: row = g*256 + 2*(t>>3) + rp, act-k = 44*(t&7) + 4*ki (+2*hw per uint).
// act coords: [h(256) | fx(64) | fz(32)] = 352; r/z cols: h->W_hh, x->W_ih.
__global__ __launch_bounds__(256) void repack_rz(const float* __restrict__ W_ih,
                                                 const float* __restrict__ W_hh,
                                                 uint_t* __restrict__ slab) {
    int uid = blockIdx.x * 256 + threadIdx.x;     // uints, total 44*1024*2
    if (uid >= 44 * 1024 * 2) return;
    int n = uid >> 11, rem = uid & 2047, t = rem >> 1, hw = rem & 1;
    int g = (n < 22) ? 0 : 1, n2 = n - g * 22;
    int rp = n2 / 11, ki = n2 % 11;
    int row = g * 256 + 2 * (t >> 3) + rp;
    int ak = 44 * (t & 7) + 4 * ki + 2 * hw;
    float v0 = (ak < 256) ? W_hh[row * 256 + ak] : W_ih[row * 96 + ak - 256];
    float v1 = (ak + 1 < 256) ? W_hh[row * 256 + ak + 1] : W_ih[row * 96 + ak + 1 - 256];
    slab[uid] = pk2(v0, v1);
}

// hn weights, lane-linear uint4 units: hnws4[i*1024 + t], i = rp*4 + b:
// row = 512 + 2*(t>>3) + rp, k = 8*((t&7) + 8*b) .. +8  (strided k-blocks).
__global__ __launch_bounds__(256) void repack_hn(const float* __restrict__ W_hh,
                                                 uint_t* __restrict__ hnws) {
    int uid = blockIdx.x * 256 + threadIdx.x;     // uints, total 8*1024*4
    if (uid >= 8 * 1024 * 4) return;
    int i = uid >> 12, rem = uid & 4095, t = rem >> 2, w = rem & 3;
    int rp = i >> 2, b = i & 3;
    int row = 512 + 2 * (t >> 3) + rp;
    int k0 = 8 * ((t & 7) + 8 * b) + 2 * w;
    hnws[uid] = pk2(W_hh[row * 256 + k0], W_hh[row * 256 + k0 + 1]);
}

// in-gate weights streamed: uint2 units wig2[u*1024 + t], u = rp*3 + ui:
// row = 512 + 2*(t>>3) + rp, xk = 12*(t&7) + 4*ui (+2*hw).
__global__ __launch_bounds__(256) void repack_in(const float* __restrict__ W_ih,
                                                 uint_t* __restrict__ wig) {
    int uid = blockIdx.x * 256 + threadIdx.x;     // uints, total 6*1024*2
    if (uid >= 6 * 1024 * 2) return;
    int u = uid >> 11, rem = uid & 2047, t = rem >> 1, hw = rem & 1;
    int rp = u / 3, ui = u % 3;
    int row = 512 + 2 * (t >> 3) + rp;
    int xk = 12 * (t & 7) + 4 * ui + 2 * hw;
    wig[uid] = pk2(W_ih[row * 96 + xk], W_ih[row * 96 + xk + 1]);
}

// phi weights f16: [c(0..3 loc, 4..7 scale)][160 uints] (padded to 162 when copied to LDS)
__global__ __launch_bounds__(256) void repack_wp(const float* __restrict__ Wp_loc,
                                                 const float* __restrict__ Wp_scale,
                                                 uint_t* __restrict__ wpg) {
    int uid = blockIdx.x * 256 + threadIdx.x;
    if (uid >= 8 * 160) return;
    int c = uid / 160, u = uid % 160;
    const float* src = (c < 4) ? (Wp_loc + c * 320) : (Wp_scale + (c - 4) * 320);
    wpg[uid] = pk2(src[2 * u], src[2 * u + 1]);
}

// theta weights f16: [38][144 uints], k-order cat(fz, h)
__global__ __launch_bounds__(256) void repack_wt(const float* __restrict__ Wt_loc,
                                                 uint_t* __restrict__ wtg) {
    int uid = blockIdx.x * 256 + threadIdx.x;
    if (uid >= 38 * 144) return;
    wtg[uid] = pk2(Wt_loc[2 * uid], Wt_loc[2 * uid + 1]);
}

// fx = relu(x @ Wx^T + bx) for all (b,l), stored f16-packed [B][L][64].
__global__ __launch_bounds__(256) void fx_pre(const float* __restrict__ x,
                                              const float* __restrict__ Wx,
                                              const float* __restrict__ bx,
                                              ushort_t* __restrict__ fxbuf) {
    __shared__ float w[FXN][FN + 1];
    __shared__ float bxs[FXN];
    int t = threadIdx.x;
    for (int i = t; i < FXN * FN; i += 256) w[i / FN][i % FN] = Wx[i];
    if (t < FXN) bxs[t] = bx[t];
    __syncthreads();
    size_t id = (size_t)blockIdx.x * 256 + t;
    const float* xr = x + id * FN;
    float xv[FN];
#pragma unroll
    for (int f = 0; f < FN; ++f) xv[f] = xr[f];
    uint4* dst = (uint4*)(fxbuf + id * FXN);
#pragma unroll
    for (int e8 = 0; e8 < 8; ++e8) {
        float a[8];
#pragma unroll
        for (int u = 0; u < 8; ++u) {
            int e = e8 * 8 + u;
            float acc = bxs[e];
#pragma unroll
            for (int f = 0; f < FN; ++f) acc += xv[f] * w[e][f];
            a[u] = fmaxf(acc, 0.0f);
        }
        uint4 o;
        o.x = pk2(a[0], a[1]); o.y = pk2(a[2], a[3]);
        o.z = pk2(a[4], a[5]); o.w = pk2(a[6], a[7]);
        dst[e8] = o;
    }
}

// r/z dot unit u (4 act-k): acts shared across 2 rows x 2 m, weights from regs.
#define RZU(u) { \
    uint2 a0 = A0_2[11 * s8 + (u)]; \
    uint2 a1 = A1_2[11 * s8 + (u)]; \
    uint2 wa = wrA[u], wb = wrB[u]; \
    r00 = dot2h(wa.x, a0.x, r00); r00 = dot2h(wa.y, a0.y, r00); \
    r01 = dot2h(wb.x, a0.x, r01); r01 = dot2h(wb.y, a0.y, r01); \
    r10 = dot2h(wa.x, a1.x, r10); r10 = dot2h(wa.y, a1.y, r10); \
    r11 = dot2h(wb.x, a1.x, r11); r11 = dot2h(wb.y, a1.y, r11); \
    uint2 za = wzA[u], zb = wzB[u]; \
    z00 = dot2h(za.x, a0.x, z00); z00 = dot2h(za.y, a0.y, z00); \
    z01 = dot2h(zb.x, a0.x, z01); z01 = dot2h(zb.y, a0.y, z01); \
    z10 = dot2h(za.x, a1.x, z10); z10 = dot2h(za.y, a1.y, z10); \
    z11 = dot2h(zb.x, a1.x, z11); z11 = dot2h(zb.y, a1.y, z11); }

// 3-stage full butterfly over the 8 k-slice lanes
#define BF(v) { v += __shfl_xor(v, 1); v += __shfl_xor(v, 2); v += __shfl_xor(v, 4); }

template <bool FXPRE>
__global__ __launch_bounds__(NT, 1)
void vrnn_main(
    const float* __restrict__ x, const float* __restrict__ eps,
    const float* __restrict__ Wx, const float* __restrict__ bx,
    const float* __restrict__ Wz1, const float* __restrict__ bz1,
    const float* __restrict__ Wz2, const float* __restrict__ bz2,
    const float* __restrict__ bp_loc, const float* __restrict__ bp_scale,
    const float* __restrict__ bt_loc,
    const float* __restrict__ b_ih, const float* __restrict__ b_hh,
    const uint_t* __restrict__ slab, const uint_t* __restrict__ hnsrc,
    const uint_t* __restrict__ wig, const uint_t* __restrict__ wpg,
    const uint_t* __restrict__ wtg, const ushort_t* __restrict__ fxbuf,
    float* __restrict__ out)
{
    __shared__ __attribute__((aligned(16))) uint_t hnw[8 * 1024 * 4];   // 128 KB lane-linear
    __shared__ uint_t wpH[8 * 162];                                     // phi weights (padded)
    __shared__ __attribute__((aligned(16))) uint_t actp[2][2][176];     // f16 acts, dbuf
    __shared__ float pp[2][8][16];
    __shared__ float bsr[HN], bsz[HN], bin_[HN], bhn_[HN];
    __shared__ float wz1s[16][ZDN];
    __shared__ float wz2s[FZN][16];
    __shared__ float bz1s[16], bz2s[FZN], btls[FN], bpls[ZDN], bpss[ZDN];
    __shared__ float epsb[2][ZDN];

    const int t = threadIdx.x;
    const int b0 = blockIdx.x * 2;
    const int jp = t >> 3, s8 = t & 7;

    // ---- one-time LDS init
    {
        uint4* hd = (uint4*)hnw;
        const uint4* hs = (const uint4*)hnsrc;
        for (int i = t; i < 8 * 1024; i += NT) hd[i] = hs[i];
    }
    for (int i = t; i < 8 * 160; i += NT) wpH[(i / 160) * 162 + (i % 160)] = wpg[i];
    if (t < 256) {
        bsr[t] = b_ih[t] + b_hh[t];
        bsz[t] = b_ih[HN + t] + b_hh[HN + t];
        bin_[t] = b_ih[2 * HN + t];
        bhn_[t] = b_hh[2 * HN + t];
    }
    if (t >= 256 && t < 320) ((float*)wz1s)[t - 256] = Wz1[t - 256];
    if (t >= 320 && t < 832) ((float*)wz2s)[t - 320] = Wz2[t - 320];
    if (t >= 832 && t < 848) bz1s[t - 832] = bz1[t - 832];
    if (t >= 848 && t < 880) bz2s[t - 848] = bz2[t - 848];
    if (t >= 880 && t < 880 + FN) btls[t - 880] = bt_loc[t - 880];
    if (t >= 928 && t < 932) bpls[t - 928] = bp_loc[t - 928];
    if (t >= 936 && t < 940) bpss[t - 936] = bp_scale[t - 936];
    // zero h region of buffer 0; prefill l=0 eps / fx
    if (t < 256) actp[0][t >> 7][t & 127] = 0u;
    if (t >= 256 && t < 264) {
        int m = ((t - 256) >> 2) & 1, c = t & 3;
        epsb[m][c] = eps[(size_t)(b0 + m) * ZDN + c];
    }
    if (FXPRE && t >= 272 && t < 304) {
        int tt = t - 272, m = tt >> 4, part = tt & 15;
        uint2 v = ((const uint2*)(fxbuf + ((size_t)(b0 + m) * LN) * FXN))[part];
        actp[0][m][128 + 2 * part] = v.x;
        actp[0][m][129 + 2 * part] = v.y;
    }

    // ---- persistent register weights: r,z = 44 uint2 = 88 VGPRs
    const uint2* S2 = (const uint2*)slab;
    uint2 wrA[11], wrB[11], wzA[11], wzB[11];
#pragma unroll
    for (int k = 0; k < 11; ++k) {
        wrA[k] = S2[k * 1024 + t];
        wrB[k] = S2[(11 + k) * 1024 + t];
        wzA[k] = S2[(22 + k) * 1024 + t];
        wzB[k] = S2[(33 + k) * 1024 + t];
    }

    float h_own = 0.0f;     // lanes s8<4: h(m = s8>>1, j = 2*jp + (s8&1))
    __syncthreads();

#pragma unroll 1
    for (int l = 0; l < LN; ++l) {
        const int cur = l & 1, nxt = cur ^ 1;
        const uint_t* Au0 = actp[cur][0];
        const uint_t* Au1 = actp[cur][1];
        const uint2* A0_2 = (const uint2*)Au0;
        const uint2* A1_2 = (const uint2*)Au1;
        const uint4* A0_4 = (const uint4*)Au0;
        const uint4* A1_4 = (const uint4*)Au1;

        // ---- (tier B only): fx + eps in-loop
        if (!FXPRE) {
            if (t < 64) {
                int m = t >> 5, e2 = t & 31;
                const float* xr = x + ((size_t)(b0 + m) * LN + l) * FN;
                float a0 = bx[2 * e2], a1 = bx[2 * e2 + 1];
                const float* w0 = Wx + (2 * e2) * FN;
                const float* w1 = w0 + FN;
#pragma unroll
                for (int f = 0; f < FN; ++f) { float xv = xr[f]; a0 += xv * w0[f]; a1 += xv * w1[f]; }
                actp[cur][m][128 + e2] = pk2(fmaxf(a0, 0.0f), fmaxf(a1, 0.0f));
            }
            if (t >= 64 && t < 72) {
                int m = (t >> 2) & 1, c = t & 3;
                epsb[m][c] = eps[((size_t)l * BN + b0 + m) * ZDN + c];
            }
            __syncthreads();
        }

        // ---- P2: phi partials (t<256) + issue next-step prefetch
        if (t < 256) {
            int m = t >> 7, r = t & 127, c = r >> 4, ks = r & 15;
            const uint2* wv = (const uint2*)&wpH[c * 162 + ks * 10];
            const uint2* av = (const uint2*)((m ? Au1 : Au0) + ks * 10);
            float acc = 0.0f;
#pragma unroll
            for (int i = 0; i < 5; ++i) {
                uint2 w = wv[i], a = av[i];
                acc = dot2h(w.x, a.x, acc); acc = dot2h(w.y, a.y, acc);
            }
            pp[m][c][ks] = acc;
        }
        float pf_eps = 0.0f;
        uint2 pf_fx = {0, 0};
        if (FXPRE) {
            int lp = (l + 1 < LN) ? l + 1 : LN - 1;
            if (t >= 952 && t < 960) {
                int tt = t - 952, m = tt >> 2, c = tt & 3;
                pf_eps = eps[((size_t)lp * BN + b0 + m) * ZDN + c];
            }
            if (t >= 960 && t < 992) {
                int tt = t - 960, m = tt >> 4, part = tt & 15;
                pf_fx = ((const uint2*)(fxbuf + ((size_t)(b0 + m) * LN + lp) * FXN))[part];
            }
        }
        __syncthreads();   // sync1: pp ready

        // ---- P3: CDE (t<64) overlapped with r/z dots (fz-free units)
        if (t < 64) {
            int m = t >> 5, qq = t & 31;
            float zz[ZDN];
#pragma unroll
            for (int c = 0; c < ZDN; ++c) {
                float lo = bpls[c], sc = bpss[c];
#pragma unroll
                for (int ks = 0; ks < 16; ++ks) { lo += pp[m][c][ks]; sc += pp[m][c + 4][ks]; }
                zz[c] = lo + softplusf_(sc) * epsb[m][c];
            }
            float acc = bz2s[qq];
#pragma unroll
            for (int k = 0; k < 16; ++k) {
                float a = bz1s[k];
#pragma unroll
                for (int c = 0; c < ZDN; ++c) a += zz[c] * wz1s[k][c];
                acc += fmaxf(a, 0.0f) * wz2s[qq][k];
            }
            float v = fmaxf(acc, 0.0f);
            float oth = __shfl_xor(v, 1);
            if (!(qq & 1)) actp[cur][m][160 + (qq >> 1)] = pk2(v, oth);
        }

        float r00 = 0, r01 = 0, r10 = 0, r11 = 0;
        float z00 = 0, z01 = 0, z10 = 0, z11 = 0;
#pragma unroll
        for (int u = 0; u < 3; ++u) RZU(u)
        if (s8 != 7) {
#pragma unroll
            for (int u = 3; u < 11; ++u) RZU(u)
        }
        __syncthreads();   // sync2: fz ready

        // ---- P4: fz-dependent tail, combines, hn, in, theta, gate update
        if (s8 == 7) {
#pragma unroll
            for (int u = 3; u < 11; ++u) RZU(u)
        }
        BF(r00) BF(r01) BF(r10) BF(r11) BF(z00) BF(z01) BF(z10) BF(z11)
        const int m_own = s8 >> 1, rp_own = s8 & 1;
        float gr = m_own ? (rp_own ? r11 : r10) : (rp_own ? r01 : r00);
        float gz = m_own ? (rp_own ? z11 : z10) : (rp_own ? z01 : z00);

        // hn gate: LDS lane-linear weights, strided k-blocks (conflict-free)
        float h00 = 0, h01 = 0, h10 = 0, h11 = 0;
        {
            const uint4* hn4 = (const uint4*)hnw;
#pragma unroll
            for (int b = 0; b < 4; ++b) {
                uint4 a0 = A0_4[s8 + 8 * b];
                uint4 a1 = A1_4[s8 + 8 * b];
                uint4 w0 = hn4[b * 1024 + t];
                uint4 w1 = hn4[(4 + b) * 1024 + t];
                h00 = dot2h(w0.x, a0.x, h00); h00 = dot2h(w0.y, a0.y, h00);
                h00 = dot2h(w0.z, a0.z, h00); h00 = dot2h(w0.w, a0.w, h00);
                h01 = dot2h(w1.x, a0.x, h01); h01 = dot2h(w1.y, a0.y, h01);
                h01 = dot2h(w1.z, a0.z, h01); h01 = dot2h(w1.w, a0.w, h01);
                h10 = dot2h(w0.x, a1.x, h10); h10 = dot2h(w0.y, a1.y, h10);
                h10 = dot2h(w0.z, a1.z, h10); h10 = dot2h(w0.w, a1.w, h10);
                h11 = dot2h(w1.x, a1.x, h11); h11 = dot2h(w1.y, a1.y, h11);
                h11 = dot2h(w1.z, a1.z, h11); h11 = dot2h(w1.w, a1.w, h11);
            }
        }
        BF(h00) BF(h01) BF(h10) BF(h11)
        float gh = m_own ? (rp_own ? h11 : h10) : (rp_own ? h01 : h00);

        // in gate: weights streamed from L2 (sequenced loads, low reg pressure)
        float i00 = 0, i01 = 0, i10 = 0, i11 = 0;
        {
            const uint2* G2 = (const uint2*)wig;
#pragma unroll
            for (int ui = 0; ui < 3; ++ui) {
                uint2 w0 = G2[ui * 1024 + t];
                uint2 w1 = G2[(3 + ui) * 1024 + t];
                uint2 a0 = A0_2[64 + 3 * s8 + ui];
                uint2 a1 = A1_2[64 + 3 * s8 + ui];
                i00 = dot2h(w0.x, a0.x, i00); i00 = dot2h(w0.y, a0.y, i00);
                i01 = dot2h(w1.x, a0.x, i01); i01 = dot2h(w1.y, a0.y, i01);
                i10 = dot2h(w0.x, a1.x, i10); i10 = dot2h(w0.y, a1.y, i10);
                i11 = dot2h(w1.x, a1.x, i11); i11 = dot2h(w1.y, a1.y, i11);
            }
        }
        BF(i00) BF(i01) BF(i10) BF(i11)
        float gi = m_own ? (rp_own ? i11 : i10) : (rp_own ? i01 : i00);

        // theta (t in [320,624)): streamed weights, 4-way k-split
        if (t >= 320 && t < 624) {
            int tt = t - 320, o = tt >> 2, s4 = tt & 3, f = o >> 1, m = o & 1;
            const uint4* wt4 = ((const uint4*)wtg) + f * 36;
            const uint4* ap = m ? A1_4 : A0_4;
            float acc = 0.0f;
#pragma unroll
            for (int i2 = 0; i2 < 9; ++i2) {
                int i = s4 * 9 + i2;
                uint4 w = wt4[i];
                uint4 a = (i < 4) ? ap[40 + i] : ap[i - 4];   // fz | h
                acc = dot2h(w.x, a.x, acc); acc = dot2h(w.y, a.y, acc);
                acc = dot2h(w.z, a.z, acc); acc = dot2h(w.w, a.w, acc);
            }
            acc += __shfl_xor(acc, 1);
            acc += __shfl_xor(acc, 2);
            if (!s4) out[((size_t)(b0 + m) * LN + l) * FN + f] = acc + btls[f];
        }

        // gate math + h update: lanes s8<4 own (m_own, j = 2jp + rp_own)
        if (s8 < 4) {
            int j = 2 * jp + rp_own;
            float r_ = sigmoidf_(gr + bsr[j]);
            float z_ = sigmoidf_(gz + bsz[j]);
            float n_ = tanhf(gi + bin_[j] + r_ * (gh + bhn_[j]));
            float hnew = (1.0f - z_) * n_ + z_ * h_own;
            h_own = hnew;
            float hp = __shfl_xor(hnew, 1);            // pair rows j, j^1 (lanes c, c^1)
            if (!rp_own) actp[nxt][m_own][jp] = pk2(hnew, hp);
        }

        // park prefetched inputs into next-step buffers
        if (FXPRE) {
            if (t >= 952 && t < 960) {
                int tt = t - 952, m = tt >> 2, c = tt & 3;
                epsb[m][c] = pf_eps;
            }
            if (t >= 960 && t < 992) {
                int tt = t - 960, m = tt >> 4, part = tt & 15;
                actp[nxt][m][128 + 2 * part] = pf_fx.x;
                actp[nxt][m][129 + 2 * part] = pf_fx.y;
            }
        }
        __syncthreads();   // sync3
    }
}

extern "C" void kernel_launch(void* const* d_in, const int* in_sizes, int n_in,
                              void* d_out, int out_size, void* d_ws, size_t ws_size,
                              hipStream_t stream) {
    const float* x        = (const float*)d_in[0];
    const float* eps      = (const float*)d_in[1];
    const float* Wx       = (const float*)d_in[2];
    const float* bx       = (const float*)d_in[3];
    const float* Wz1      = (const float*)d_in[4];
    const float* bz1      = (const float*)d_in[5];
    const float* Wz2      = (const float*)d_in[6];
    const float* bz2      = (const float*)d_in[7];
    const float* Wp_loc   = (const float*)d_in[8];
    const float* bp_loc   = (const float*)d_in[9];
    const float* Wp_scale = (const float*)d_in[10];
    const float* bp_scale = (const float*)d_in[11];
    const float* Wt_loc   = (const float*)d_in[12];
    const float* bt_loc   = (const float*)d_in[13];
    const float* W_ih     = (const float*)d_in[16];
    const float* W_hh     = (const float*)d_in[17];
    const float* b_ih     = (const float*)d_in[18];
    const float* b_hh     = (const float*)d_in[19];
    float* out = (float*)d_out;

    const size_t slabU = (size_t)44 * 1024 * 2;   // uints
    const size_t hnU   = (size_t)8 * 1024 * 4;
    const size_t wigU  = (size_t)6 * 1024 * 2;
    const size_t wpU   = 8 * 160;
    const size_t wtU   = 38 * 144;
    const size_t fxS   = (size_t)BN * LN * FXN;   // shorts

    uint_t* slab  = (uint_t*)d_ws;
    uint_t* hnsrc = slab + slabU;
    uint_t* wig   = hnsrc + hnU;
    uint_t* wpg   = wig + wigU;
    uint_t* wtg   = wpg + wpU;
    ushort_t* fxbuf = (ushort_t*)(wtg + wtU);

    repack_rz<<<(int)((slabU + 255) / 256), 256, 0, stream>>>(W_ih, W_hh, slab);
    repack_hn<<<(int)((hnU + 255) / 256), 256, 0, stream>>>(W_hh, hnsrc);
    repack_in<<<(int)((wigU + 255) / 256), 256, 0, stream>>>(W_ih, wig);
    repack_wp<<<5, 256, 0, stream>>>(Wp_loc, Wp_scale, wpg);
    repack_wt<<<22, 256, 0, stream>>>(Wt_loc, wtg);

    if (ws_size >= (slabU + hnU + wigU + wpU + wtU) * 4 + fxS * 2) {
        fx_pre<<<BN * LN / 256, 256, 0, stream>>>(x, Wx, bx, fxbuf);
        vrnn_main<true><<<NWG, NT, 0, stream>>>(
            x, eps, Wx, bx, Wz1, bz1, Wz2, bz2, bp_loc, bp_scale, bt_loc,
            b_ih, b_hh, slab, hnsrc, wig, wpg, wtg, fxbuf, out);
    } else {
        vrnn_main<false><<<NWG, NT, 0, stream>>>(
            x, eps, Wx, bx, Wz1, bz1, Wz2, bz2, bp_loc, bp_scale, bt_loc,
            b_ih, b_hh, slab, hnsrc, wig, wpg, wtg, (const ushort_t*)nullptr, out);
    }
}